// Round 3
// baseline (69.166 us; speedup 1.0000x reference)
//
#include <hip/hip_runtime.h>
#include <math.h>

#define N 8192
#define BS 256
#define NI 16                 // i's per block
#define EPSV 1e-8f

// Single fused kernel: 512 blocks x 256 threads. Each block stages ALL of
// t[] and exp(risk[]) into LDS (64 KB -> 2 blocks/CU, 2 waves/SIMD), owns 16
// consecutive i's (4 per wave, held in registers); lanes slice the j
// dimension in float4 granularity. After the full-j accumulation each block
// applies the log + event mask for its 16 i's and atomicAdds its scaled
// contribution (-sum/N) directly to out[0] (pre-zeroed by a 4-byte memset).
__global__ __launch_bounds__(BS) void cox_fused(const float* __restrict__ risk,
                                                const float* __restrict__ t,
                                                const float* __restrict__ e,
                                                float* __restrict__ out) {
    __shared__ float sT[N];
    __shared__ float sE[N];
    __shared__ float sRed[NI];

    const int tid = threadIdx.x;

    // ---- stage t and exp(risk) into LDS, float4-vectorized ----
    const float4* t4g = (const float4*)t;
    const float4* r4g = (const float4*)risk;
    float4* sT4 = (float4*)sT;
    float4* sE4 = (float4*)sE;
    #pragma unroll
    for (int s = 0; s < N / 4 / BS; ++s) {   // 8 iterations
        int f = tid + s * BS;
        float4 tv = t4g[f];
        float4 rv = r4g[f];
        sT4[f] = tv;
        float4 ev;
        ev.x = __expf(rv.x);
        ev.y = __expf(rv.y);
        ev.z = __expf(rv.z);
        ev.w = __expf(rv.w);
        sE4[f] = ev;
    }

    const int lane = tid & 63;
    const int wave = tid >> 6;
    const int i0 = blockIdx.x * NI + wave * 4;   // this wave's 4 i's

    // t_i values from global (uniform address across lanes -> scalar load)
    float ti[4];
    #pragma unroll
    for (int m = 0; m < 4; ++m) ti[m] = t[i0 + m];

    float sum[4];
    #pragma unroll
    for (int m = 0; m < 4; ++m) sum[m] = 0.0f;

    __syncthreads();

    // ---- main loop: 32 float4-iterations per lane covers all 8192 j ----
    #pragma unroll 8
    for (int k = 0; k < N / 4 / 64; ++k) {   // 32 iterations
        int f = lane + (k << 6);
        float4 tj = sT4[f];
        float4 ej = sE4[f];
        #pragma unroll
        for (int m = 0; m < 4; ++m) {
            float s0 = (tj.x >= ti[m]) ? ej.x : 0.0f;
            float s1 = (tj.y >= ti[m]) ? ej.y : 0.0f;
            float s2 = (tj.z >= ti[m]) ? ej.z : 0.0f;
            float s3 = (tj.w >= ti[m]) ? ej.w : 0.0f;
            sum[m] += (s0 + s1) + (s2 + s3);
        }
    }

    // ---- reduce each of the 4 sums across the 64 lanes ----
    float myS = 0.0f;
    #pragma unroll
    for (int m = 0; m < 4; ++m) {
        float v = sum[m];
        v += __shfl_xor(v, 32);
        v += __shfl_xor(v, 16);
        v += __shfl_xor(v, 8);
        v += __shfl_xor(v, 4);
        v += __shfl_xor(v, 2);
        v += __shfl_xor(v, 1);
        if (lane == m) myS = v;   // lane m keeps total S for i = i0+m
    }

    float contrib = 0.0f;
    if (lane < 4) {
        int i = i0 + lane;
        contrib = e[i] * (risk[i] - __logf(myS + EPSV));
    }

    // ---- block-reduce the 16 per-i contributions, one atomic per block ----
    if (lane < 4) sRed[wave * 4 + lane] = contrib;
    __syncthreads();
    if (tid == 0) {
        float tot = 0.0f;
        #pragma unroll
        for (int x = 0; x < NI; ++x) tot += sRed[x];
        atomicAdd(out, -tot * (1.0f / (float)N));
    }
}

extern "C" void kernel_launch(void* const* d_in, const int* in_sizes, int n_in,
                              void* d_out, int out_size, void* d_ws, size_t ws_size,
                              hipStream_t stream) {
    const float* risk = (const float*)d_in[0];
    const float* t    = (const float*)d_in[1];
    const float* e    = (const float*)d_in[2];
    float* out = (float*)d_out;

    // out is poisoned to 0xAA before every timed replay; zero it so the
    // per-block atomicAdd accumulation starts from 0. (Graph-capturable.)
    hipMemsetAsync(out, 0, sizeof(float), stream);

    cox_fused<<<N / NI, BS, 0, stream>>>(risk, t, e, out);
}